// Round 8
// baseline (124.932 us; speedup 1.0000x reference)
//
#include <hip/hip_runtime.h>

// PositionalEmbedding: out[node, t*32 + j] = (child_pos(ancestor_t(node)) == j)
// N = 262144, n = 32, k = 16. Output float32 [N, 512] = 512 MiB, write-BW-bound.
// R8: R6 (load-free readlane store loop) with STRIDED row ownership:
// iteration j, wave w writes row j*NW + w, so the 4096 concurrent waves cover
// one contiguous 8 MiB band sweeping the buffer (fill-like global address
// stream) instead of 4096 private 128 KiB streams.

#define NN 32   // one-hot width (n)
#define KK 16   // ancestor depth (k)

typedef float f32x4 __attribute__((ext_vector_type(4)));

__global__ __launch_bounds__(256) void pe_fused_stride(
    const int* __restrict__ parents,
    const int* __restrict__ child_pos,
    f32x4* __restrict__ out4, int N, int n_waves)
{
    const int lane = (int)(threadIdx.x & 63);
    const int wid  = (int)((blockIdx.x * blockDim.x + threadIdx.x) >> 6);

    // ---- Phase A: lane l chases node (l * n_waves + wid) ----
    unsigned int c[4];
    {
        int cur = lane * n_waves + wid;
        if (cur >= N) cur = N;                       // sentinel (exact grid anyway)
        #pragma unroll
        for (int w = 0; w < 4; ++w) {
            unsigned int u = 0;
            #pragma unroll
            for (int b = 0; b < 4; ++b) {
                const int cp = child_pos[cur];               // independent
                const unsigned int byte = (cp < NN) ? (unsigned int)cp : 0xFFu;
                u |= byte << (8 * b);
                cur = parents[cur];                          // dependent chain
            }
            c[w] = u;
        }
    }

    // ---- Phase B: wait-free store loop; iteration j -> row j*n_waves + wid ----
    const bool hi32 = (lane >= 32);
    const int  sh   = ((lane >> 3) & 3) * 8;   // byte-in-dword shift
    const int  q4   = (lane & 7) * 4;          // one-hot quad base

    f32x4* wout = out4 + (size_t)wid * 128 + lane;     // row `wid`, float4 `lane`
    const size_t step = (size_t)n_waves * 128;         // row stride per iteration

    #pragma unroll 4
    for (int j = 0; j < 64; ++j) {
        // codes of row (j*n_waves + wid) live in lane j of this wave
        const unsigned s0 = (unsigned)__builtin_amdgcn_readlane((int)c[0], j);
        const unsigned s1 = (unsigned)__builtin_amdgcn_readlane((int)c[1], j);
        const unsigned s2 = (unsigned)__builtin_amdgcn_readlane((int)c[2], j);
        const unsigned s3 = (unsigned)__builtin_amdgcn_readlane((int)c[3], j);

        const int code0 = (int)(((hi32 ? s1 : s0) >> sh) & 0xFFu);
        const int code1 = (int)(((hi32 ? s3 : s2) >> sh) & 0xFFu);

        f32x4 v0, v1;
        v0.x = (code0 == q4    ) ? 1.0f : 0.0f;
        v0.y = (code0 == q4 + 1) ? 1.0f : 0.0f;
        v0.z = (code0 == q4 + 2) ? 1.0f : 0.0f;
        v0.w = (code0 == q4 + 3) ? 1.0f : 0.0f;
        v1.x = (code1 == q4    ) ? 1.0f : 0.0f;
        v1.y = (code1 == q4 + 1) ? 1.0f : 0.0f;
        v1.z = (code1 == q4 + 2) ? 1.0f : 0.0f;
        v1.w = (code1 == q4 + 3) ? 1.0f : 0.0f;

        wout[(size_t)j * step]      = v0;   // 1 KiB/wave, coalesced
        wout[(size_t)j * step + 64] = v1;   // 1 KiB/wave, coalesced
    }
}

extern "C" void kernel_launch(void* const* d_in, const int* in_sizes, int n_in,
                              void* d_out, int out_size, void* d_ws, size_t ws_size,
                              hipStream_t stream) {
    const int* parents   = (const int*)d_in[0];
    const int* child_pos = (const int*)d_in[1];
    f32x4* out4 = (f32x4*)d_out;

    const int N = in_sizes[0] - 1;                 // 262144
    const int n_waves = (N + 63) / 64;             // 4096 waves, 64 rows each
    const int grid    = (n_waves + 3) / 4;         // 1024 blocks of 256

    pe_fused_stride<<<grid, 256, 0, stream>>>(parents, child_pos, out4, N, n_waves);
}

// Round 9
// 111.944 us; speedup vs baseline: 1.1160x; 1.1160x over previous
//
#include <hip/hip_runtime.h>

// PositionalEmbedding: out[node, t*32 + j] = (child_pos(ancestor_t(node)) == j)
// N = 262144, n = 32, k = 16. Output float32 [N, 512] = 512 MiB, write-BW-bound.
// R9: R6 structure at FILL-LIKE OCCUPANCY. 1024 waves (1 block/CU, 1 wave/SIMD,
// ~12% occupancy, matching rocclr fill's 10.9% @ 6.7-6.9 TB/s). Each wave:
// chase 4x64 nodes (independent chains, 4-way MLP), then one contiguous
// 512 KiB store sweep via readlane (load-free, wait-free).

#define NN 32   // one-hot width (n)
#define KK 16   // ancestor depth (k)

typedef float f32x4 __attribute__((ext_vector_type(4)));

__global__ __launch_bounds__(256) void pe_fused_lo(
    const int* __restrict__ parents,
    const int* __restrict__ child_pos,
    f32x4* __restrict__ out4, int N)
{
    const int lane  = (int)(threadIdx.x & 63);
    const int wid   = (int)((blockIdx.x * blockDim.x + threadIdx.x) >> 6);
    const int wbase = wid * 256;               // first of this wave's 256 rows

    // ---- Phase A: 4 independent 16-step chases (lane l: node wbase+q*64+l) ----
    // c[q][w]: byte b of c[q][w] = code of ancestor (w*4+b) of node wbase+q*64+lane
    unsigned int c[4][4];
    int cur[4];
    #pragma unroll
    for (int q = 0; q < 4; ++q) {
        int n0 = wbase + q * 64 + lane;
        cur[q] = (n0 < N) ? n0 : N;
    }
    #pragma unroll
    for (int w = 0; w < 4; ++w) {
        unsigned int u[4] = {0, 0, 0, 0};
        #pragma unroll
        for (int b = 0; b < 4; ++b) {
            #pragma unroll
            for (int q = 0; q < 4; ++q) {       // q inner: 4-way MLP on the chain
                const int cp = child_pos[cur[q]];
                const unsigned int byte = (cp < NN) ? (unsigned int)cp : 0xFFu;
                u[q] |= byte << (8 * b);
                cur[q] = parents[cur[q]];
            }
        }
        #pragma unroll
        for (int q = 0; q < 4; ++q) c[q][w] = u[q];
    }

    // ---- Phase B: contiguous 512 KiB store sweep, load-free via readlane ----
    const bool hi32 = (lane >= 32);
    const int  sh   = ((lane >> 3) & 3) * 8;   // byte-in-dword shift
    const int  q4   = (lane & 7) * 4;          // one-hot quad base

    #pragma unroll
    for (int q = 0; q < 4; ++q) {              // static q -> c[q][*] in registers
        if (wbase + q * 64 >= N) break;        // wave-uniform guard
        f32x4* wout = out4 + (size_t)(wbase + q * 64) * 128 + lane;
        #pragma unroll 4
        for (int j = 0; j < 64; ++j) {
            const unsigned s0 = (unsigned)__builtin_amdgcn_readlane((int)c[q][0], j);
            const unsigned s1 = (unsigned)__builtin_amdgcn_readlane((int)c[q][1], j);
            const unsigned s2 = (unsigned)__builtin_amdgcn_readlane((int)c[q][2], j);
            const unsigned s3 = (unsigned)__builtin_amdgcn_readlane((int)c[q][3], j);

            const int code0 = (int)(((hi32 ? s1 : s0) >> sh) & 0xFFu);
            const int code1 = (int)(((hi32 ? s3 : s2) >> sh) & 0xFFu);

            f32x4 v0, v1;
            v0.x = (code0 == q4    ) ? 1.0f : 0.0f;
            v0.y = (code0 == q4 + 1) ? 1.0f : 0.0f;
            v0.z = (code0 == q4 + 2) ? 1.0f : 0.0f;
            v0.w = (code0 == q4 + 3) ? 1.0f : 0.0f;
            v1.x = (code1 == q4    ) ? 1.0f : 0.0f;
            v1.y = (code1 == q4 + 1) ? 1.0f : 0.0f;
            v1.z = (code1 == q4 + 2) ? 1.0f : 0.0f;
            v1.w = (code1 == q4 + 3) ? 1.0f : 0.0f;

            wout[(size_t)j * 128]      = v0;   // 1 KiB/wave, coalesced
            wout[(size_t)j * 128 + 64] = v1;   // 1 KiB/wave, coalesced
        }
    }
}

extern "C" void kernel_launch(void* const* d_in, const int* in_sizes, int n_in,
                              void* d_out, int out_size, void* d_ws, size_t ws_size,
                              hipStream_t stream) {
    const int* parents   = (const int*)d_in[0];
    const int* child_pos = (const int*)d_in[1];
    f32x4* out4 = (f32x4*)d_out;

    const int N = in_sizes[0] - 1;                 // 262144
    const int n_waves = (N + 255) / 256;           // 1024 waves, 256 rows each
    const int grid    = (n_waves + 3) / 4;         // 256 blocks of 256 threads

    pe_fused_lo<<<grid, 256, 0, stream>>>(parents, child_pos, out4, N);
}